// Round 12
// baseline (505.791 us; speedup 1.0000x reference)
//
#include <hip/hip_runtime.h>
#include <float.h>
#include <math.h>

#define NGR 64        // graphs
#define NPG0 1000     // original nodes per graph
#define HDIM 128
#define EG 16000      // edges per graph
#define NE (NGR*EG)   // 1,024,000
#define RPS 1008      // rp row stride
#define BNEPS 1e-5f
#define POOL_NB 16

typedef short short8 __attribute__((ext_vector_type(8)));
typedef float f4v __attribute__((ext_vector_type(4)));

// ---------------- fused: pool_w invnorm + conv weight bf16 hi/lo split ----------------
__global__ __launch_bounds__(256) void k_wsplit(const float* __restrict__ c1w,
    const float* __restrict__ cw, const float* __restrict__ pw,
    unsigned short* __restrict__ wh, unsigned short* __restrict__ wl,
    float* __restrict__ invnorm){
  int l = blockIdx.x, t = threadIdx.x;
  __shared__ float red[2];
  if(t < 128){
    float v = pw[l*HDIM + t];
    float s = v*v;
    #pragma unroll
    for(int o=32;o>0;o>>=1) s += __shfl_down(s, o, 64);
    if((t & 63)==0) red[t>>6] = s;
  }
  __syncthreads();
  if(t==0) invnorm[l] = 1.0f / sqrtf(red[0]+red[1]);
  int K  = (l==0) ? 64 : 128;
  int sh = (l==0) ? 6 : 7;
  const float* src = (l==0) ? c1w : (cw + (size_t)(l-1)*16384);
  int tot = 128*K;
  for(int o=t;o<tot;o+=256){
    int c = o >> sh, k = o & (K-1);
    float f = src[k*128 + c];
    unsigned u  = __float_as_uint(f);
    unsigned uh = (u + 0x7fffu + ((u>>16)&1u)) & 0xffff0000u;
    float r = f - __uint_as_float(uh);
    unsigned v = __float_as_uint(r);
    int o2 = (k>>3)*1024 + c*8 + (k&7);     // panel-major coalesced layout
    wh[(size_t)l*16384 + o2] = (unsigned short)(uh>>16);
    wl[(size_t)l*16384 + o2] = (unsigned short)((v + 0x7fffu + ((v>>16)&1u))>>16);
  }
}

// ---------------- build 1/3: per-graph-chunk LDS count + weighted degree ----------------
__global__ __launch_bounds__(256) void k_count0(const int* __restrict__ dst,
    const float* __restrict__ we, int* __restrict__ pcnt, float* __restrict__ pdeg){
  int g = blockIdx.x >> 2, sub = blockIdx.x & 3, t = threadIdx.x;
  __shared__ int   cnt[NPG0];
  __shared__ float degl[NPG0];
  for(int i=t;i<NPG0;i+=256){ cnt[i]=0; degl[i]=0.f; }
  __syncthreads();
  int base = g*EG + sub*4000;
  for(int idx=t; idx<4000; idx+=256){
    int e = base + idx;
    int ld = dst[e] - g*NPG0;
    atomicAdd(&cnt[ld], 1);
    atomicAdd(&degl[ld], we[e]);
  }
  __syncthreads();
  int p = blockIdx.x * NPG0;
  for(int i=t;i<NPG0;i+=256){ pcnt[p+i] = cnt[i]; pdeg[p+i] = degl[i]; }
}

// ---------------- build 2/3: sum partials + dinvz/gsc + exclusive scan -> rp ----------------
__global__ __launch_bounds__(1024) void k_scan(const int* __restrict__ pcnt,
    const float* __restrict__ pdeg, int* __restrict__ rp,
    float* __restrict__ dinvz, float* __restrict__ gsc){
  int g = blockIdx.x, t = threadIdx.x;
  __shared__ int sc[2][1024];
  int c = 0;
  if(t < NPG0){
    c = pcnt[(g*4+0)*NPG0+t] + pcnt[(g*4+1)*NPG0+t]
      + pcnt[(g*4+2)*NPG0+t] + pcnt[(g*4+3)*NPG0+t];
    float dg = pdeg[(g*4+0)*NPG0+t] + pdeg[(g*4+1)*NPG0+t]
             + pdeg[(g*4+2)*NPG0+t] + pdeg[(g*4+3)*NPG0+t];
    float dv = 1.0f / sqrtf(dg + 1.0f);
    dinvz[g*NPG0+t] = dv;
    gsc[g*NPG0+t]   = dv;        // layer-0 feature scale: val == 1
  }
  sc[0][t] = c;
  __syncthreads();
  int buf = 0;
  for(int d=1; d<1024; d<<=1){
    int v = sc[buf][t];
    if(t>=d) v += sc[buf][t-d];
    sc[buf^1][t] = v;
    __syncthreads();
    buf ^= 1;
  }
  if(t<=NPG0) rp[g*RPS+t] = (t==0) ? 0 : sc[buf][t-1];
}

// ---------------- build 3/3: scatter at chunk parallelism (256 blocks) ----------------
__global__ __launch_bounds__(256) void k_scatter(const int* __restrict__ src,
    const int* __restrict__ dst, const float* __restrict__ we,
    const int* __restrict__ rp, const int* __restrict__ pcnt,
    long long* __restrict__ ec){
  int g = blockIdx.x >> 2, sub = blockIdx.x & 3, t = threadIdx.x;
  __shared__ int cur[NPG0];
  for(int i=t;i<NPG0;i+=256){
    int c = rp[g*RPS+i];
    for(int s=0;s<sub;s++) c += pcnt[(g*4+s)*NPG0+i];
    cur[i] = c;
  }
  __syncthreads();
  int base = g*EG + sub*4000;
  for(int idx=t; idx<4000; idx+=256){
    int e = base + idx;
    int ld = dst[e] - g*NPG0;
    int pos = atomicAdd(&cur[ld], 1);
    ec[(size_t)g*EG + pos] = (((long long)__float_as_int(we[e]))<<32) | (unsigned)src[e];
  }
}

// ---------------- fused aggregation + MFMA GEMM + BN/ReLU + score ----------------
// Block: 16 output rows x 128 cols, grid = 4n blocks (XCD-bijective tile swizzle).
// Agg: each 16-lane GROUP owns one row. NO shfl: every lane loads the shared ec
//   record directly (same addr within group -> TA broadcast), computes c=w*gsc[s]
//   consumer-side (same FP op as producer-side -> same value), gathers h[s].
//   Pure-VMEM dependency chain; 16 unrolled independent chains pipeline in HW.
//   Padding jj clamps to a real record with c=0 -> guarded FMA skips (bitwise
//   identical accumulation to the shfl version).
// Gemm: 4 waves x 32 cols (16x16 C tiles), bf16x4 MFMA, B global panel-major.
__device__ inline void bfsplit(float f, unsigned short &h, unsigned short &l){
  unsigned u  = __float_as_uint(f);
  unsigned uh = (u + 0x7fffu + ((u>>16)&1u)) & 0xffff0000u;
  float r = f - __uint_as_float(uh);
  unsigned v = __float_as_uint(r);
  h = (unsigned short)(uh>>16);
  l = (unsigned short)((v + 0x7fffu + ((v>>16)&1u))>>16);
}

template<int KIN>
__global__ __launch_bounds__(256,3) void k_fused(const int* __restrict__ olist,
    const int* __restrict__ rp, const long long* __restrict__ ec,
    const float* __restrict__ dinvz, const float* __restrict__ gsc,
    const float* __restrict__ h,
    const unsigned short* __restrict__ Wh, const unsigned short* __restrict__ Wl,
    const float* __restrict__ bias, const float* __restrict__ gamma,
    const float* __restrict__ beta, const float* __restrict__ mean,
    const float* __restrict__ var, const float* __restrict__ pw,
    const float* __restrict__ invn_p, float* __restrict__ hout,
    float* __restrict__ score){
  constexpr int L0 = (KIN==64);
  __shared__ __attribute__((aligned(16))) unsigned short AsH[16*KIN];
  __shared__ __attribute__((aligned(16))) unsigned short AsL[16*KIN];
  __shared__ float sp[16][4];
  int t = threadIdx.x;
  // XCD-aware bijective block->tile remap (m204): residue class b%8 (one XCD)
  // owns a contiguous tile range -> each XCD's L2 sees only ~8 graphs' h slices.
  int nb = gridDim.x, b = blockIdx.x;
  int q = nb >> 3, r = nb & 7;
  int xcd = b & 7, boff = b >> 3;
  int tile = (xcd < r) ? (xcd*(q+1) + boff) : (r*(q+1) + (xcd-r)*q + boff);
  int r0 = tile * 16;
  const int lane = t & 63, wid = t >> 6;
  const int qw = lane >> 4, sl16 = lane & 15;

  // ---- phase 1: each 16-lane group aggregates its own row into LDS ----
  {
    int local = wid*4 + qw;                     // row within block
    int row = r0 + local;                       // global compact row
    int d = L0 ? row : olist[row];              // original id
    int g = d / NPG0;
    int ld = d - g*NPG0;
    int e0 = rp[g*RPS+ld], e1 = rp[g*RPS+ld+1];
    float dvd = dinvz[d];
    float gsd = gsc[d];
    float4 a0; a0.x=0.f; a0.y=0.f; a0.z=0.f; a0.w=0.f;
    float4 a1; a1.x=0.f; a1.y=0.f; a1.z=0.f; a1.w=0.f;
    const long long* ecg = ec + (size_t)g*EG;
    for(int b2=e0;b2<e1;b2+=16){
      int mm = e1-b2; if(mm>16) mm=16;
      #pragma unroll
      for(int jj=0;jj<16;jj++){
        int ej = b2 + ((jj<mm) ? jj : (mm-1));  // padding clamps to a real record
        long long p = ecg[ej];                  // group-shared addr: TA broadcast
        float w = __int_as_float((int)(p>>32));
        int s = (int)(p & 0xffffffffLL);
        float c = (jj<mm) ? w*gsc[s] : 0.f;     // dead src or padding -> c==0
        if(L0){
          float4 hv = *(const float4*)(h + (size_t)s*64 + 4*sl16);
          if(c != 0.f){
            a0.x += c*hv.x; a0.y += c*hv.y; a0.z += c*hv.z; a0.w += c*hv.w;
          }
        } else {
          const float4* hp = (const float4*)(h + (size_t)s*HDIM + 8*sl16);
          float4 h0 = hp[0], h1 = hp[1];
          if(c != 0.f){
            a0.x += c*h0.x; a0.y += c*h0.y; a0.z += c*h0.z; a0.w += c*h0.w;
            a1.x += c*h1.x; a1.y += c*h1.y; a1.z += c*h1.z; a1.w += c*h1.w;
          }
        }
      }
    }
    // self-loop + bfsplit + LDS write (all 16 lanes of the group)
    if(L0){
      float4 hs = *(const float4*)(h + (size_t)d*64 + 4*sl16);
      float4 o;
      o.x = dvd*(a0.x + gsd*hs.x); o.y = dvd*(a0.y + gsd*hs.y);
      o.z = dvd*(a0.z + gsd*hs.z); o.w = dvd*(a0.w + gsd*hs.w);
      ushort4 h4, l4;
      bfsplit(o.x, h4.x, l4.x); bfsplit(o.y, h4.y, l4.y);
      bfsplit(o.z, h4.z, l4.z); bfsplit(o.w, h4.w, l4.w);
      int off2 = (local*128 + sl16*8) ^ ((local&7)<<4);
      *(ushort4*)((char*)AsH + off2) = h4;
      *(ushort4*)((char*)AsL + off2) = l4;
    } else {
      const float4* hp = (const float4*)(h + (size_t)d*HDIM + 8*sl16);
      float4 s0 = hp[0], s1 = hp[1];
      float4 o0, o1;
      o0.x = dvd*(a0.x + gsd*s0.x); o0.y = dvd*(a0.y + gsd*s0.y);
      o0.z = dvd*(a0.z + gsd*s0.z); o0.w = dvd*(a0.w + gsd*s0.w);
      o1.x = dvd*(a1.x + gsd*s1.x); o1.y = dvd*(a1.y + gsd*s1.y);
      o1.z = dvd*(a1.z + gsd*s1.z); o1.w = dvd*(a1.w + gsd*s1.w);
      ushort4 h4, l4;
      int off2 = (local*256 + sl16*16) ^ ((local&7)<<4);
      bfsplit(o0.x, h4.x, l4.x); bfsplit(o0.y, h4.y, l4.y);
      bfsplit(o0.z, h4.z, l4.z); bfsplit(o0.w, h4.w, l4.w);
      *(ushort4*)((char*)AsH + off2) = h4;
      *(ushort4*)((char*)AsL + off2) = l4;
      bfsplit(o1.x, h4.x, l4.x); bfsplit(o1.y, h4.y, l4.y);
      bfsplit(o1.z, h4.z, l4.z); bfsplit(o1.w, h4.w, l4.w);
      *(ushort4*)((char*)AsH + off2 + 8) = h4;
      *(ushort4*)((char*)AsL + off2 + 8) = l4;
    }
  }
  __syncthreads();

  // ---- phase 2: MFMA gemm (wave wid -> cols wid*32..+31, 2 n-tiles) ----
  f4v acc[2];
  #pragma unroll
  for(int n=0;n<2;n++){ acc[n][0]=0.f; acc[n][1]=0.f; acc[n][2]=0.f; acc[n][3]=0.f; }
  #pragma unroll
  for(int ks=0; ks<KIN/32; ks++){
    short8 ah, al, bh[2], bl[2];
    int kb = ks*64 + qw*16;           // byte offset within A row
    int panel = ks*4 + qw;            // k-panel index (8 shorts wide)
    #pragma unroll
    for(int n=0;n<2;n++){
      int col = wid*32 + n*16 + sl16;
      int goff = (panel*128 + col)*8;
      bh[n] = *(const short8*)(Wh + goff);
      bl[n] = *(const short8*)(Wl + goff);
    }
    {
      int row = sl16;
      int off2 = (row*(KIN*2) + kb) ^ ((row&7)<<4);
      ah = *(const short8*)((const char*)AsH + off2);
      al = *(const short8*)((const char*)AsL + off2);
    }
    #pragma unroll
    for(int n=0;n<2;n++){
      acc[n] = __builtin_amdgcn_mfma_f32_16x16x32_bf16(ah, bh[n], acc[n], 0,0,0);
      acc[n] = __builtin_amdgcn_mfma_f32_16x16x32_bf16(ah, bl[n], acc[n], 0,0,0);
      acc[n] = __builtin_amdgcn_mfma_f32_16x16x32_bf16(al, bh[n], acc[n], 0,0,0);
      acc[n] = __builtin_amdgcn_mfma_f32_16x16x32_bf16(al, bl[n], acc[n], 0,0,0);
    }
  }

  // epilogue: bias + BN + ReLU, scatter rows, per-row pool-score partials
  float invn = invn_p[0];
  float bi[2], scv[2], bt[2], mn[2], pv[2];
  #pragma unroll
  for(int n=0;n<2;n++){
    int c = wid*32 + n*16 + sl16;
    bi[n]  = bias[c];
    scv[n] = gamma[c] * (1.0f/sqrtf(var[c] + BNEPS));
    bt[n]  = beta[c];
    mn[n]  = mean[c];
    pv[n]  = pw[c];
  }
  #pragma unroll
  for(int i=0;i<4;i++){
    int rl  = qw*4 + i;               // C/D: row=(lane>>4)*4+reg, col=lane&15
    int row = r0 + rl;
    int orig = olist ? olist[row] : row;
    float p = 0.f;
    #pragma unroll
    for(int n=0;n<2;n++){
      float v = fmaxf((acc[n][i] + bi[n] - mn[n])*scv[n] + bt[n], 0.f);
      hout[(size_t)orig*HDIM + wid*32 + n*16 + sl16] = v;
      p += v*pv[n];
    }
    p += __shfl_xor(p, 1, 64); p += __shfl_xor(p, 2, 64);
    p += __shfl_xor(p, 4, 64); p += __shfl_xor(p, 8, 64);
    if(sl16==0) sp[rl][wid] = p;
  }
  __syncthreads();
  if(t < 16) score[r0 + t] = tanhf(((sp[t][0]+sp[t][1]) + (sp[t][2]+sp[t][3])) * invn);
}

// ---------------- per-graph top-k: exact radix-select on float keys ----------------
__global__ __launch_bounds__(512) void k_topk(int n, int k,
    const float* __restrict__ score, const int* __restrict__ curlist,
    float* __restrict__ vals, int* __restrict__ nextlist,
    float* __restrict__ dinvz, float* __restrict__ gsc){
  int g = blockIdx.x, t = threadIdx.x;
  __shared__ unsigned keys[1024];
  __shared__ int hist[256];
  __shared__ int ssum[256];
  __shared__ int sc2[2][512];
  __shared__ int eqbuf[1024];
  __shared__ int eqn;
  __shared__ int sh_B, sh_need, sh_E, sh_cut;
  __shared__ unsigned sh_pref;
  // load + order-preserving bijection to unsigned (bigger float -> bigger key)
  for(int i=t;i<n;i+=512){
    unsigned b = __float_as_uint(score[g*n+i]);
    keys[i] = (b & 0x80000000u) ? ~b : (b | 0x80000000u);
  }
  if(t==0){ sh_need = k; sh_pref = 0u; sh_cut = 0x7fffffff; }
  __syncthreads();
  for(int pass=0; pass<4; pass++){
    int shift = 24 - 8*pass;
    if(t<256) hist[t]=0;
    __syncthreads();
    unsigned pref = sh_pref; int need = sh_need;
    for(int i=t;i<n;i+=512){
      unsigned u = keys[i];
      bool m = (pass==0) || ((u >> (shift+8)) == pref);
      if(m) atomicAdd(&hist[(u>>shift)&255], 1);
    }
    __syncthreads();
    if(t<256) ssum[t] = hist[t];
    __syncthreads();
    for(int d=1; d<256; d<<=1){
      int v=0;
      if(t<256) v = ssum[t] + ((t+d<256)? ssum[t+d] : 0);
      __syncthreads();
      if(t<256) ssum[t] = v;
      __syncthreads();
    }
    if(t<256){
      int Sgt = ssum[t] - hist[t];           // count of keys strictly above bucket t
      if(Sgt < need && need <= ssum[t]) sh_B = t;
    }
    __syncthreads();
    int B = sh_B;
    if(t==0){
      sh_need = need - (ssum[B] - hist[B]);
      sh_pref = (pass==0) ? (unsigned)B : ((pref<<8) | (unsigned)B);
      if(pass==3) sh_E = hist[B];
    }
    __syncthreads();
  }
  unsigned T = sh_pref; int r_eq = sh_need; int E = sh_E;
  if(E > r_eq){
    // rare: multiple elements equal to threshold; keep the r_eq smallest indices
    if(t==0) eqn = 0;
    __syncthreads();
    for(int i=t;i<n;i+=512) if(keys[i]==T){ int p=atomicAdd(&eqn,1); eqbuf[p]=i; }
    __syncthreads();
    if(t==0){
      int last = -1;
      for(int j=0;j<r_eq;j++){
        int mn = 0x7fffffff;
        for(int q2=0;q2<E;q2++){ int v=eqbuf[q2]; if(v>last && v<mn) mn=v; }
        last = mn;
      }
      sh_cut = last;                      // kept equals: idx <= sh_cut
    }
    __syncthreads();
  }
  int cut = sh_cut;
  int c0=0, c1=0;
  {
    int i=t;
    if(i<n){ unsigned u=keys[i]; c0 = (u>T) || (u==T && i<=cut); }
    i=t+512;
    if(i<n){ unsigned u=keys[i]; c1 = (u>T) || (u==T && i<=cut); }
  }
  sc2[0][t] = c0+c1;
  __syncthreads();
  int buf=0;
  for(int d=1; d<512; d<<=1){
    int v = sc2[buf][t];
    if(t>=d) v += sc2[buf][t-d];
    sc2[buf^1][t]=v;
    __syncthreads();
    buf^=1;
  }
  int base = (t==0) ? 0 : sc2[buf][t-1];
  {
    int i=t;
    if(i<n){
      int orig = curlist ? curlist[g*n+i] : (g*NPG0 + i);
      if(c0){
        unsigned u=keys[i];
        float f = __uint_as_float((u & 0x80000000u) ? (u ^ 0x80000000u) : ~u);
        vals[g*k+base]=f; nextlist[g*k+base]=orig; base++;
      } else { dinvz[orig]=0.f; gsc[orig]=0.f; }
    }
    i=t+512;
    if(i<n){
      int orig = curlist ? curlist[g*n+i] : (g*NPG0 + i);
      if(c1){
        unsigned u=keys[i];
        float f = __uint_as_float((u & 0x80000000u) ? (u ^ 0x80000000u) : ~u);
        vals[g*k+base]=f; nextlist[g*k+base]=orig;
      } else { dinvz[orig]=0.f; gsc[orig]=0.f; }
    }
  }
}

// ---------------- pool partials + next-layer degree + gsc ----------------
// Degree pass reads the graph's dinvz slice from an LDS snapshot (alive flag is
// stable: concurrent updates keep nonzero; zeros were set by the prior topk).
__global__ __launch_bounds__(256) void k_gpd(int k, int do_deg,
    const float* __restrict__ hraw, const float* __restrict__ vals,
    const int* __restrict__ nextlist,
    float* __restrict__ sumst, float* __restrict__ maxst,
    const int* __restrict__ rp, const long long* __restrict__ ec,
    float* __restrict__ dinvz, float* __restrict__ gsc){
  int g = blockIdx.x & 63;
  int chunk = blockIdx.x >> 6;               // 0..POOL_NB-1
  int wid = threadIdx.x >> 6, lane = threadIdx.x & 63;
  int ww = chunk*4 + wid;                    // wave id within graph: 0..POOL_NB*4-1
  const int half = lane >> 5, sl32 = lane & 31;
  const int qw   = lane >> 4, sl16 = lane & 15;
  __shared__ float sdz[NPG0];
  if(do_deg){
    for(int i=threadIdx.x;i<NPG0;i+=256) sdz[i] = dinvz[g*NPG0+i];
    __syncthreads();
  }
  const int NH = POOL_NB*4*2;                // half-waves per graph
  float4 psum; psum.x=0.f; psum.y=0.f; psum.z=0.f; psum.w=0.f;
  float4 pmax; pmax.x=-FLT_MAX; pmax.y=-FLT_MAX; pmax.z=-FLT_MAX; pmax.w=-FLT_MAX;
  for(int j = ww*2 + half; j < k; j += NH){
    float v = vals[g*k+j];
    int d = nextlist[g*k+j];
    float4 hv = *(const float4*)(hraw + (size_t)d*HDIM + 4*sl32);
    float4 o; o.x=hv.x*v; o.y=hv.y*v; o.z=hv.z*v; o.w=hv.w*v;
    psum.x+=o.x; psum.y+=o.y; psum.z+=o.z; psum.w+=o.w;
    pmax.x=fmaxf(pmax.x,o.x); pmax.y=fmaxf(pmax.y,o.y);
    pmax.z=fmaxf(pmax.z,o.z); pmax.w=fmaxf(pmax.w,o.w);
  }
  if(do_deg){
    const int NQ = POOL_NB*4*4;              // quarter-waves per graph
    for(int j = ww*4 + qw; j < k; j += NQ){
      int d  = nextlist[g*k + j];
      int ld = d - g*NPG0;
      int e0 = rp[g*RPS+ld], e1 = rp[g*RPS+ld+1];
      float deg = 0.f;
      for(int b=e0+sl16; b<e1; b+=16){
        long long rec = ec[(size_t)g*EG + b];
        int s = (int)(rec & 0xffffffffLL);
        float w = __int_as_float((int)(rec>>32));
        if(sdz[s - g*NPG0] != 0.f) deg += w;
      }
      #pragma unroll
      for(int o=8;o>0;o>>=1) deg += __shfl_xor(deg, o, 64);  // within 16-lane group
      if(sl16==0){
        float dv = 1.0f / sqrtf(deg + 1.0f);
        dinvz[d] = dv;
        gsc[d] = dv * vals[g*k+j];
      }
    }
  }
  // cross-half reduce (each half covered all 128 features for its row subset)
  psum.x += __shfl_xor(psum.x, 32, 64); psum.y += __shfl_xor(psum.y, 32, 64);
  psum.z += __shfl_xor(psum.z, 32, 64); psum.w += __shfl_xor(psum.w, 32, 64);
  pmax.x = fmaxf(pmax.x, __shfl_xor(pmax.x, 32, 64));
  pmax.y = fmaxf(pmax.y, __shfl_xor(pmax.y, 32, 64));
  pmax.z = fmaxf(pmax.z, __shfl_xor(pmax.z, 32, 64));
  pmax.w = fmaxf(pmax.w, __shfl_xor(pmax.w, 32, 64));
  __shared__ float ss[4][128];
  __shared__ float sm[4][128];
  if(half==0){
    *(float4*)&ss[wid][4*sl32] = psum;
    *(float4*)&sm[wid][4*sl32] = pmax;
  }
  __syncthreads();
  int t = threadIdx.x;
  if(t < 128){
    float s = (ss[0][t]+ss[1][t]) + (ss[2][t]+ss[3][t]);
    float m = fmaxf(fmaxf(sm[0][t], sm[1][t]), fmaxf(sm[2][t], sm[3][t]));
    sumst[(size_t)(chunk*NGR + g)*HDIM + t] = s;
    maxst[(size_t)(chunk*NGR + g)*HDIM + t] = m;
  }
}

// ---------------- MLP head (folds 6 layers x POOL_NB chunk partials) ----------------
__global__ __launch_bounds__(512) void k_head(const float* __restrict__ sumstage,
    const float* __restrict__ maxstage,
    const float* __restrict__ d1w, const float* __restrict__ d1b,
    const float* __restrict__ d2w, const float* __restrict__ d2b, float* __restrict__ out){
  const float kinv[6] = {1.f/800.f, 1.f/640.f, 1.f/512.f, 1.f/410.f, 1.f/328.f, 1.f/263.f};
  int g = blockIdx.x, j = threadIdx.x;
  __shared__ float fl[256];
  __shared__ float hd[512];
  if(j < 128){
    float s = 0.f;
    #pragma unroll
    for(int l=0;l<6;l++){
      float ls = 0.f;
      for(int c=0;c<POOL_NB;c++)
        ls += sumstage[(size_t)((l*POOL_NB + c)*NGR + g)*HDIM + j];
      s += ls * kinv[l];
    }
    fl[j] = s;
  } else if(j < 256){
    int f = j - 128;
    float m = 0.f;
    #pragma unroll
    for(int l=0;l<6;l++){
      float lm = -FLT_MAX;
      for(int c=0;c<POOL_NB;c++)
        lm = fmaxf(lm, maxstage[(size_t)((l*POOL_NB + c)*NGR + g)*HDIM + f]);
      m += lm;
    }
    fl[j] = m;
  }
  __syncthreads();
  float acc = d1b[j];
  for(int i=0;i<256;i++) acc += fl[i]*d1w[i*512+j];
  hd[j] = fmaxf(acc, 0.f);
  __syncthreads();
  if(j < 10){
    float a = d2b[j];
    for(int i=0;i<512;i++) a += hd[i]*d2w[i*10+j];
    out[g*10+j] = a;
  }
}

extern "C" void kernel_launch(void* const* d_in, const int* in_sizes, int n_in,
                              void* d_out, int out_size, void* d_ws, size_t ws_size,
                              hipStream_t stream) {
  const float* x    = (const float*)d_in[0];
  const int* ei     = (const int*)d_in[1];
  const float* ew   = (const float*)d_in[3];
  const float* conv1w = (const float*)d_in[4];
  const float* convw  = (const float*)d_in[5];
  const float* convb  = (const float*)d_in[6];
  const float* bng    = (const float*)d_in[7];
  const float* bnb    = (const float*)d_in[8];
  const float* bnm    = (const float*)d_in[9];
  const float* bnv    = (const float*)d_in[10];
  const float* poolw  = (const float*)d_in[11];
  const float* d1w    = (const float*)d_in[12];
  const float* d1b    = (const float*)d_in[13];
  const float* d2w    = (const float*)d_in[14];
  const float* d2b    = (const float*)d_in[15];
  float* out = (float*)d_out;

  char* w = (char*)d_ws;
  float* hbufA = (float*)w; w += (size_t)64000*128*4;   // layer output ping
  float* hbufB = (float*)w; w += (size_t)64000*128*4;   // layer output pong
  long long* ec = (long long*)w; w += (size_t)NE*8;     // static (w, src_orig), dst-bucketed
  int*   rp    = (int*)w;   w += (size_t)NGR*RPS*4;
  int*   pcnt  = (int*)w;   w += (size_t)256*NPG0*4;
  float* pdeg  = (float*)w; w += (size_t)256*NPG0*4;
  float* dinvz = (float*)w; w += (size_t)64000*4;       // 0 == node dead (alive indicator)
  float* gsc   = (float*)w; w += (size_t)64000*4;       // dinv_new * topk_val (0 == dead)
  float* score = (float*)w; w += (size_t)64000*4;
  float* vals  = (float*)w; w += (size_t)51200*4;
  int*   listA = (int*)w;   w += (size_t)51200*4;
  int*   listB = (int*)w;   w += (size_t)51200*4;
  float* invno = (float*)w; w += 64;
  float* sumstage = (float*)w; w += (size_t)6*POOL_NB*NGR*HDIM*4;
  float* maxstage = (float*)w; w += (size_t)6*POOL_NB*NGR*HDIM*4;
  unsigned short* whi = (unsigned short*)w; w += (size_t)6*16384*2;  // bf16-hi weights, panel-major
  unsigned short* wlo = (unsigned short*)w; w += (size_t)6*16384*2;  // bf16-lo weights

  k_wsplit<<<6,256,0,stream>>>(conv1w, convw, poolw, whi, wlo, invno);

  const int ns[6]={1000,800,640,512,410,328};
  const int ks[6]={800,640,512,410,328,263};

  // ---- one-time CSR build: count (256 blk) -> scan (64 blk) -> scatter (256 blk) ----
  k_count0<<<256,256,0,stream>>>(ei+NE, ew, pcnt, pdeg);
  k_scan<<<64,1024,0,stream>>>(pcnt, pdeg, rp, dinvz, gsc);
  k_scatter<<<256,256,0,stream>>>(ei, ei+NE, ew, rp, pcnt, ec);

  // ---- layer 0 (input = x, 64 cols) ----
  k_fused<64><<<4000,256,0,stream>>>(nullptr, rp, ec, dinvz, gsc, x, whi, wlo,
                                     convb, bng, bnb, bnm, bnv, poolw, invno,
                                     hbufA, score);
  k_topk<<<64,512,0,stream>>>(1000, 800, score, nullptr, vals, listA, dinvz, gsc);
  k_gpd<<<64*POOL_NB,256,0,stream>>>(800, 1, hbufA, vals, listA,
                                     sumstage, maxstage, rp, ec, dinvz, gsc);

  // ---- layers 1..5 (ping-pong h buffers: fused reads hin, writes hout) ----
  int* cur = listA; int* nxt = listB;
  float* hin = hbufA; float* hot = hbufB;
  for(int i=1;i<6;i++){
    int n = ns[i], k = ks[i];
    k_fused<128><<<4*n,256,0,stream>>>(cur, rp, ec, dinvz, gsc, hin,
                                       whi + (size_t)i*16384, wlo + (size_t)i*16384,
                                       convb+i*128, bng+i*128, bnb+i*128, bnm+i*128,
                                       bnv+i*128, poolw+i*128, invno+i,
                                       hot, score);
    k_topk<<<64,512,0,stream>>>(n, k, score, cur, vals, nxt, dinvz, gsc);
    k_gpd<<<64*POOL_NB,256,0,stream>>>(k, (i<5)?1:0, hot, vals, nxt,
                                       sumstage + (size_t)i*POOL_NB*NGR*HDIM,
                                       maxstage + (size_t)i*POOL_NB*NGR*HDIM,
                                       rp, ec, dinvz, gsc);
    int* tmp = cur; cur = nxt; nxt = tmp;
    float* htmp = hin; hin = hot; hot = htmp;
  }

  k_head<<<64,512,0,stream>>>(sumstage, maxstage, d1w, d1b, d2w, d2b, out);
}

// Round 13
// 422.281 us; speedup vs baseline: 1.1978x; 1.1978x over previous
//
#include <hip/hip_runtime.h>
#include <float.h>
#include <math.h>

#define NGR 64        // graphs
#define NPG0 1000     // original nodes per graph
#define HDIM 128
#define EG 16000      // edges per graph
#define NE (NGR*EG)   // 1,024,000
#define RPS 1008      // rp row stride
#define BNEPS 1e-5f
#define POOL_NB 16

typedef short short8 __attribute__((ext_vector_type(8)));
typedef float f4v __attribute__((ext_vector_type(4)));

// ---------------- fused: pool_w invnorm + conv weight bf16 hi/lo split ----------------
__global__ __launch_bounds__(256) void k_wsplit(const float* __restrict__ c1w,
    const float* __restrict__ cw, const float* __restrict__ pw,
    unsigned short* __restrict__ wh, unsigned short* __restrict__ wl,
    float* __restrict__ invnorm){
  int l = blockIdx.x, t = threadIdx.x;
  __shared__ float red[2];
  if(t < 128){
    float v = pw[l*HDIM + t];
    float s = v*v;
    #pragma unroll
    for(int o=32;o>0;o>>=1) s += __shfl_down(s, o, 64);
    if((t & 63)==0) red[t>>6] = s;
  }
  __syncthreads();
  if(t==0) invnorm[l] = 1.0f / sqrtf(red[0]+red[1]);
  int K  = (l==0) ? 64 : 128;
  int sh = (l==0) ? 6 : 7;
  const float* src = (l==0) ? c1w : (cw + (size_t)(l-1)*16384);
  int tot = 128*K;
  for(int o=t;o<tot;o+=256){
    int c = o >> sh, k = o & (K-1);
    float f = src[k*128 + c];
    unsigned u  = __float_as_uint(f);
    unsigned uh = (u + 0x7fffu + ((u>>16)&1u)) & 0xffff0000u;
    float r = f - __uint_as_float(uh);
    unsigned v = __float_as_uint(r);
    int o2 = (k>>3)*1024 + c*8 + (k&7);     // panel-major coalesced layout
    wh[(size_t)l*16384 + o2] = (unsigned short)(uh>>16);
    wl[(size_t)l*16384 + o2] = (unsigned short)((v + 0x7fffu + ((v>>16)&1u))>>16);
  }
}

// ---------------- build phase: per-graph-chunk LDS count + weighted degree ----------------
__global__ __launch_bounds__(256) void k_count0(const int* __restrict__ dst,
    const float* __restrict__ we, int* __restrict__ pcnt, float* __restrict__ pdeg){
  int g = blockIdx.x >> 2, sub = blockIdx.x & 3, t = threadIdx.x;
  __shared__ int   cnt[NPG0];
  __shared__ float degl[NPG0];
  for(int i=t;i<NPG0;i+=256){ cnt[i]=0; degl[i]=0.f; }
  __syncthreads();
  int base = g*EG + sub*4000;
  for(int idx=t; idx<4000; idx+=256){
    int e = base + idx;
    int ld = dst[e] - g*NPG0;
    atomicAdd(&cnt[ld], 1);
    atomicAdd(&degl[ld], we[e]);
  }
  __syncthreads();
  int p = blockIdx.x * NPG0;
  for(int i=t;i<NPG0;i+=256){ pcnt[p+i] = cnt[i]; pdeg[p+i] = degl[i]; }
}

// ---------------- fused scan + scatter: block g owns graph g ----------------
__global__ __launch_bounds__(1024) void k_build(const int* __restrict__ pcnt,
    const float* __restrict__ pdeg, const int* __restrict__ src,
    const int* __restrict__ dst, const float* __restrict__ we,
    int* __restrict__ rp, float* __restrict__ dinvz, float* __restrict__ gsc,
    long long* __restrict__ ec){
  int g = blockIdx.x, t = threadIdx.x;
  __shared__ int sc[2][1024];
  __shared__ int cur[NPG0];
  int c = 0;
  if(t < NPG0){
    c = pcnt[(g*4+0)*NPG0+t] + pcnt[(g*4+1)*NPG0+t]
      + pcnt[(g*4+2)*NPG0+t] + pcnt[(g*4+3)*NPG0+t];
    float dg = pdeg[(g*4+0)*NPG0+t] + pdeg[(g*4+1)*NPG0+t]
             + pdeg[(g*4+2)*NPG0+t] + pdeg[(g*4+3)*NPG0+t];
    float dv = 1.0f / sqrtf(dg + 1.0f);
    dinvz[g*NPG0+t] = dv;
    gsc[g*NPG0+t]   = dv;        // layer-0 feature scale: val == 1
  }
  sc[0][t] = c;
  __syncthreads();
  int buf = 0;
  for(int d=1; d<1024; d<<=1){
    int v = sc[buf][t];
    if(t>=d) v += sc[buf][t-d];
    sc[buf^1][t] = v;
    __syncthreads();
    buf ^= 1;
  }
  if(t<=NPG0) rp[g*RPS+t] = (t==0) ? 0 : sc[buf][t-1];
  if(t<NPG0)  cur[t]      = (t==0) ? 0 : sc[buf][t-1];
  __syncthreads();
  int base = g*EG;
  for(int idx=t; idx<EG; idx+=1024){
    int e = base + idx;
    int ld = dst[e] - g*NPG0;
    int pos = atomicAdd(&cur[ld], 1);
    ec[(size_t)base + pos] = (((long long)__float_as_int(we[e]))<<32) | (unsigned)src[e];
  }
}

// ---------------- fused aggregation + MFMA GEMM + BN/ReLU + score ----------------
// Block: 16 output rows x 128 cols, grid = 4n blocks (XCD-bijective tile swizzle).
// Agg: each 16-lane GROUP owns one row end-to-end: loads its ~deg records in one
//   16-wide batch, broadcasts within group, gathers 512B/record, accumulates
//   privately, writes straight to the swizzled LDS A-tile (16 chains/block).
// Gemm: 4 waves x 32 cols (16x16 C tiles), bf16x4 MFMA, B global panel-major.
__device__ inline void bfsplit(float f, unsigned short &h, unsigned short &l){
  unsigned u  = __float_as_uint(f);
  unsigned uh = (u + 0x7fffu + ((u>>16)&1u)) & 0xffff0000u;
  float r = f - __uint_as_float(uh);
  unsigned v = __float_as_uint(r);
  h = (unsigned short)(uh>>16);
  l = (unsigned short)((v + 0x7fffu + ((v>>16)&1u))>>16);
}

template<int KIN>
__global__ __launch_bounds__(256) void k_fused(const int* __restrict__ olist,
    const int* __restrict__ rp, const long long* __restrict__ ec,
    const float* __restrict__ dinvz, const float* __restrict__ gsc,
    const float* __restrict__ h,
    const unsigned short* __restrict__ Wh, const unsigned short* __restrict__ Wl,
    const float* __restrict__ bias, const float* __restrict__ gamma,
    const float* __restrict__ beta, const float* __restrict__ mean,
    const float* __restrict__ var, const float* __restrict__ pw,
    const float* __restrict__ invn_p, float* __restrict__ hout,
    float* __restrict__ score){
  constexpr int L0 = (KIN==64);
  __shared__ __attribute__((aligned(16))) unsigned short AsH[16*KIN];
  __shared__ __attribute__((aligned(16))) unsigned short AsL[16*KIN];
  __shared__ float sp[16][4];
  int t = threadIdx.x;
  // XCD-aware bijective block->tile remap (m204): residue class b%8 (one XCD)
  // owns a contiguous tile range -> each XCD's L2 sees only ~8 graphs' h slices.
  int nb = gridDim.x, b = blockIdx.x;
  int q = nb >> 3, r = nb & 7;
  int xcd = b & 7, boff = b >> 3;
  int tile = (xcd < r) ? (xcd*(q+1) + boff) : (r*(q+1) + (xcd-r)*q + boff);
  int r0 = tile * 16;
  const int lane = t & 63, wid = t >> 6;
  const int qw = lane >> 4, sl16 = lane & 15;

  // ---- phase 1: each 16-lane group aggregates its own row into LDS ----
  {
    int local = wid*4 + qw;                     // row within block
    int row = r0 + local;                       // global compact row
    int d = L0 ? row : olist[row];              // original id
    int g = d / NPG0;
    int ld = d - g*NPG0;
    int e0 = rp[g*RPS+ld], e1 = rp[g*RPS+ld+1];
    float dvd = dinvz[d];
    float gsd = gsc[d];
    float4 a0; a0.x=0.f; a0.y=0.f; a0.z=0.f; a0.w=0.f;
    float4 a1; a1.x=0.f; a1.y=0.f; a1.z=0.f; a1.w=0.f;
    for(int b2=e0;b2<e1;b2+=16){
      int mm = e1-b2; if(mm>16) mm=16;
      long long rec = (sl16<mm) ? ec[(size_t)g*EG + b2 + sl16] : 0;
      int   sl = (int)(rec & 0xffffffffLL);
      float cl = __int_as_float((int)(rec>>32)) * gsc[sl];
      long long pk = (((long long)__float_as_int(cl))<<32) | (unsigned)sl;
      for(int jj=0;jj<mm;jj++){
        long long p = __shfl(pk, (qw<<4) + jj, 64);   // broadcast within group
        float c = __int_as_float((int)(p>>32));
        if(c != 0.f){
          int s = (int)(p & 0xffffffffLL);
          if(L0){
            float4 hv = *(const float4*)(h + (size_t)s*64 + 4*sl16);
            a0.x += c*hv.x; a0.y += c*hv.y; a0.z += c*hv.z; a0.w += c*hv.w;
          } else {
            const float4* hp = (const float4*)(h + (size_t)s*HDIM + 8*sl16);
            float4 h0 = hp[0], h1 = hp[1];
            a0.x += c*h0.x; a0.y += c*h0.y; a0.z += c*h0.z; a0.w += c*h0.w;
            a1.x += c*h1.x; a1.y += c*h1.y; a1.z += c*h1.z; a1.w += c*h1.w;
          }
        }
      }
    }
    // self-loop + bfsplit + LDS write (all 16 lanes of the group)
    if(L0){
      float4 hs = *(const float4*)(h + (size_t)d*64 + 4*sl16);
      float4 o;
      o.x = dvd*(a0.x + gsd*hs.x); o.y = dvd*(a0.y + gsd*hs.y);
      o.z = dvd*(a0.z + gsd*hs.z); o.w = dvd*(a0.w + gsd*hs.w);
      ushort4 h4, l4;
      bfsplit(o.x, h4.x, l4.x); bfsplit(o.y, h4.y, l4.y);
      bfsplit(o.z, h4.z, l4.z); bfsplit(o.w, h4.w, l4.w);
      int off2 = (local*128 + sl16*8) ^ ((local&7)<<4);
      *(ushort4*)((char*)AsH + off2) = h4;
      *(ushort4*)((char*)AsL + off2) = l4;
    } else {
      const float4* hp = (const float4*)(h + (size_t)d*HDIM + 8*sl16);
      float4 s0 = hp[0], s1 = hp[1];
      float4 o0, o1;
      o0.x = dvd*(a0.x + gsd*s0.x); o0.y = dvd*(a0.y + gsd*s0.y);
      o0.z = dvd*(a0.z + gsd*s0.z); o0.w = dvd*(a0.w + gsd*s0.w);
      o1.x = dvd*(a1.x + gsd*s1.x); o1.y = dvd*(a1.y + gsd*s1.y);
      o1.z = dvd*(a1.z + gsd*s1.z); o1.w = dvd*(a1.w + gsd*s1.w);
      ushort4 h4, l4;
      int off2 = (local*256 + sl16*16) ^ ((local&7)<<4);
      bfsplit(o0.x, h4.x, l4.x); bfsplit(o0.y, h4.y, l4.y);
      bfsplit(o0.z, h4.z, l4.z); bfsplit(o0.w, h4.w, l4.w);
      *(ushort4*)((char*)AsH + off2) = h4;
      *(ushort4*)((char*)AsL + off2) = l4;
      bfsplit(o1.x, h4.x, l4.x); bfsplit(o1.y, h4.y, l4.y);
      bfsplit(o1.z, h4.z, l4.z); bfsplit(o1.w, h4.w, l4.w);
      *(ushort4*)((char*)AsH + off2 + 8) = h4;
      *(ushort4*)((char*)AsL + off2 + 8) = l4;
    }
  }
  __syncthreads();

  // ---- phase 2: MFMA gemm (wave wid -> cols wid*32..+31, 2 n-tiles) ----
  f4v acc[2];
  #pragma unroll
  for(int n=0;n<2;n++){ acc[n][0]=0.f; acc[n][1]=0.f; acc[n][2]=0.f; acc[n][3]=0.f; }
  #pragma unroll
  for(int ks=0; ks<KIN/32; ks++){
    short8 ah, al, bh[2], bl[2];
    int kb = ks*64 + qw*16;           // byte offset within A row
    int panel = ks*4 + qw;            // k-panel index (8 shorts wide)
    #pragma unroll
    for(int n=0;n<2;n++){
      int col = wid*32 + n*16 + sl16;
      int goff = (panel*128 + col)*8;
      bh[n] = *(const short8*)(Wh + goff);
      bl[n] = *(const short8*)(Wl + goff);
    }
    {
      int row = sl16;
      int off2 = (row*(KIN*2) + kb) ^ ((row&7)<<4);
      ah = *(const short8*)((const char*)AsH + off2);
      al = *(const short8*)((const char*)AsL + off2);
    }
    #pragma unroll
    for(int n=0;n<2;n++){
      acc[n] = __builtin_amdgcn_mfma_f32_16x16x32_bf16(ah, bh[n], acc[n], 0,0,0);
      acc[n] = __builtin_amdgcn_mfma_f32_16x16x32_bf16(ah, bl[n], acc[n], 0,0,0);
      acc[n] = __builtin_amdgcn_mfma_f32_16x16x32_bf16(al, bh[n], acc[n], 0,0,0);
      acc[n] = __builtin_amdgcn_mfma_f32_16x16x32_bf16(al, bl[n], acc[n], 0,0,0);
    }
  }

  // epilogue: bias + BN + ReLU, scatter rows, per-row pool-score partials
  float invn = invn_p[0];
  float bi[2], scv[2], bt[2], mn[2], pv[2];
  #pragma unroll
  for(int n=0;n<2;n++){
    int c = wid*32 + n*16 + sl16;
    bi[n]  = bias[c];
    scv[n] = gamma[c] * (1.0f/sqrtf(var[c] + BNEPS));
    bt[n]  = beta[c];
    mn[n]  = mean[c];
    pv[n]  = pw[c];
  }
  #pragma unroll
  for(int i=0;i<4;i++){
    int rl  = qw*4 + i;               // C/D: row=(lane>>4)*4+reg, col=lane&15
    int row = r0 + rl;
    int orig = olist ? olist[row] : row;
    float p = 0.f;
    #pragma unroll
    for(int n=0;n<2;n++){
      float v = fmaxf((acc[n][i] + bi[n] - mn[n])*scv[n] + bt[n], 0.f);
      hout[(size_t)orig*HDIM + wid*32 + n*16 + sl16] = v;
      p += v*pv[n];
    }
    p += __shfl_xor(p, 1, 64); p += __shfl_xor(p, 2, 64);
    p += __shfl_xor(p, 4, 64); p += __shfl_xor(p, 8, 64);
    if(sl16==0) sp[rl][wid] = p;
  }
  __syncthreads();
  if(t < 16) score[r0 + t] = tanhf(((sp[t][0]+sp[t][1]) + (sp[t][2]+sp[t][3])) * invn);
}

// ---------------- per-graph top-k: exact radix-select on float keys ----------------
__global__ __launch_bounds__(512) void k_topk(int n, int k,
    const float* __restrict__ score, const int* __restrict__ curlist,
    float* __restrict__ vals, int* __restrict__ nextlist,
    float* __restrict__ dinvz, float* __restrict__ gsc){
  int g = blockIdx.x, t = threadIdx.x;
  __shared__ unsigned keys[1024];
  __shared__ int hist[256];
  __shared__ int ssum[256];
  __shared__ int sc2[2][512];
  __shared__ int eqbuf[1024];
  __shared__ int eqn;
  __shared__ int sh_B, sh_need, sh_E, sh_cut;
  __shared__ unsigned sh_pref;
  // load + order-preserving bijection to unsigned (bigger float -> bigger key)
  for(int i=t;i<n;i+=512){
    unsigned b = __float_as_uint(score[g*n+i]);
    keys[i] = (b & 0x80000000u) ? ~b : (b | 0x80000000u);
  }
  if(t==0){ sh_need = k; sh_pref = 0u; sh_cut = 0x7fffffff; }
  __syncthreads();
  for(int pass=0; pass<4; pass++){
    int shift = 24 - 8*pass;
    if(t<256) hist[t]=0;
    __syncthreads();
    unsigned pref = sh_pref; int need = sh_need;
    for(int i=t;i<n;i+=512){
      unsigned u = keys[i];
      bool m = (pass==0) || ((u >> (shift+8)) == pref);
      if(m) atomicAdd(&hist[(u>>shift)&255], 1);
    }
    __syncthreads();
    if(t<256) ssum[t] = hist[t];
    __syncthreads();
    for(int d=1; d<256; d<<=1){
      int v=0;
      if(t<256) v = ssum[t] + ((t+d<256)? ssum[t+d] : 0);
      __syncthreads();
      if(t<256) ssum[t] = v;
      __syncthreads();
    }
    if(t<256){
      int Sgt = ssum[t] - hist[t];           // count of keys strictly above bucket t
      if(Sgt < need && need <= ssum[t]) sh_B = t;
    }
    __syncthreads();
    int B = sh_B;
    if(t==0){
      sh_need = need - (ssum[B] - hist[B]);
      sh_pref = (pass==0) ? (unsigned)B : ((pref<<8) | (unsigned)B);
      if(pass==3) sh_E = hist[B];
    }
    __syncthreads();
  }
  unsigned T = sh_pref; int r_eq = sh_need; int E = sh_E;
  if(E > r_eq){
    // rare: multiple elements equal to threshold; keep the r_eq smallest indices
    if(t==0) eqn = 0;
    __syncthreads();
    for(int i=t;i<n;i+=512) if(keys[i]==T){ int p=atomicAdd(&eqn,1); eqbuf[p]=i; }
    __syncthreads();
    if(t==0){
      int last = -1;
      for(int j=0;j<r_eq;j++){
        int mn = 0x7fffffff;
        for(int q2=0;q2<E;q2++){ int v=eqbuf[q2]; if(v>last && v<mn) mn=v; }
        last = mn;
      }
      sh_cut = last;                      // kept equals: idx <= sh_cut
    }
    __syncthreads();
  }
  int cut = sh_cut;
  int c0=0, c1=0;
  {
    int i=t;
    if(i<n){ unsigned u=keys[i]; c0 = (u>T) || (u==T && i<=cut); }
    i=t+512;
    if(i<n){ unsigned u=keys[i]; c1 = (u>T) || (u==T && i<=cut); }
  }
  sc2[0][t] = c0+c1;
  __syncthreads();
  int buf=0;
  for(int d=1; d<512; d<<=1){
    int v = sc2[buf][t];
    if(t>=d) v += sc2[buf][t-d];
    sc2[buf^1][t]=v;
    __syncthreads();
    buf^=1;
  }
  int base = (t==0) ? 0 : sc2[buf][t-1];
  {
    int i=t;
    if(i<n){
      int orig = curlist ? curlist[g*n+i] : (g*NPG0 + i);
      if(c0){
        unsigned u=keys[i];
        float f = __uint_as_float((u & 0x80000000u) ? (u ^ 0x80000000u) : ~u);
        vals[g*k+base]=f; nextlist[g*k+base]=orig; base++;
      } else { dinvz[orig]=0.f; gsc[orig]=0.f; }
    }
    i=t+512;
    if(i<n){
      int orig = curlist ? curlist[g*n+i] : (g*NPG0 + i);
      if(c1){
        unsigned u=keys[i];
        float f = __uint_as_float((u & 0x80000000u) ? (u ^ 0x80000000u) : ~u);
        vals[g*k+base]=f; nextlist[g*k+base]=orig;
      } else { dinvz[orig]=0.f; gsc[orig]=0.f; }
    }
  }
}

// ---------------- pool partials + next-layer degree + gsc ----------------
__global__ __launch_bounds__(256) void k_gpd(int k, int do_deg,
    const float* __restrict__ hraw, const float* __restrict__ vals,
    const int* __restrict__ nextlist,
    float* __restrict__ sumst, float* __restrict__ maxst,
    const int* __restrict__ rp, const long long* __restrict__ ec,
    float* __restrict__ dinvz, float* __restrict__ gsc){
  int g = blockIdx.x & 63;
  int chunk = blockIdx.x >> 6;               // 0..POOL_NB-1
  int wid = threadIdx.x >> 6, lane = threadIdx.x & 63;
  int ww = chunk*4 + wid;                    // wave id within graph: 0..POOL_NB*4-1
  const int half = lane >> 5, sl32 = lane & 31;
  const int qw   = lane >> 4, sl16 = lane & 15;
  const int NH = POOL_NB*4*2;                // half-waves per graph
  float4 psum; psum.x=0.f; psum.y=0.f; psum.z=0.f; psum.w=0.f;
  float4 pmax; pmax.x=-FLT_MAX; pmax.y=-FLT_MAX; pmax.z=-FLT_MAX; pmax.w=-FLT_MAX;
  for(int j = ww*2 + half; j < k; j += NH){
    float v = vals[g*k+j];
    int d = nextlist[g*k+j];
    float4 hv = *(const float4*)(hraw + (size_t)d*HDIM + 4*sl32);
    float4 o; o.x=hv.x*v; o.y=hv.y*v; o.z=hv.z*v; o.w=hv.w*v;
    psum.x+=o.x; psum.y+=o.y; psum.z+=o.z; psum.w+=o.w;
    pmax.x=fmaxf(pmax.x,o.x); pmax.y=fmaxf(pmax.y,o.y);
    pmax.z=fmaxf(pmax.z,o.z); pmax.w=fmaxf(pmax.w,o.w);
  }
  if(do_deg){
    const int NQ = POOL_NB*4*4;              // quarter-waves per graph
    for(int j = ww*4 + qw; j < k; j += NQ){
      int d  = nextlist[g*k + j];
      int ld = d - g*NPG0;
      int e0 = rp[g*RPS+ld], e1 = rp[g*RPS+ld+1];
      float deg = 0.f;
      for(int b=e0+sl16; b<e1; b+=16){
        long long rec = ec[(size_t)g*EG + b];
        int s = (int)(rec & 0xffffffffLL);
        float w = __int_as_float((int)(rec>>32));
        if(dinvz[s] != 0.f) deg += w;
      }
      #pragma unroll
      for(int o=8;o>0;o>>=1) deg += __shfl_xor(deg, o, 64);  // within 16-lane group
      if(sl16==0){
        float dv = 1.0f / sqrtf(deg + 1.0f);
        dinvz[d] = dv;
        gsc[d] = dv * vals[g*k+j];
      }
    }
  }
  // cross-half reduce (each half covered all 128 features for its row subset)
  psum.x += __shfl_xor(psum.x, 32, 64); psum.y += __shfl_xor(psum.y, 32, 64);
  psum.z += __shfl_xor(psum.z, 32, 64); psum.w += __shfl_xor(psum.w, 32, 64);
  pmax.x = fmaxf(pmax.x, __shfl_xor(pmax.x, 32, 64));
  pmax.y = fmaxf(pmax.y, __shfl_xor(pmax.y, 32, 64));
  pmax.z = fmaxf(pmax.z, __shfl_xor(pmax.z, 32, 64));
  pmax.w = fmaxf(pmax.w, __shfl_xor(pmax.w, 32, 64));
  __shared__ float ss[4][128];
  __shared__ float sm[4][128];
  if(half==0){
    *(float4*)&ss[wid][4*sl32] = psum;
    *(float4*)&sm[wid][4*sl32] = pmax;
  }
  __syncthreads();
  int t = threadIdx.x;
  if(t < 128){
    float s = (ss[0][t]+ss[1][t]) + (ss[2][t]+ss[3][t]);
    float m = fmaxf(fmaxf(sm[0][t], sm[1][t]), fmaxf(sm[2][t], sm[3][t]));
    sumst[(size_t)(chunk*NGR + g)*HDIM + t] = s;
    maxst[(size_t)(chunk*NGR + g)*HDIM + t] = m;
  }
}

// ---------------- MLP head (folds 6 layers x POOL_NB chunk partials) ----------------
__global__ __launch_bounds__(512) void k_head(const float* __restrict__ sumstage,
    const float* __restrict__ maxstage,
    const float* __restrict__ d1w, const float* __restrict__ d1b,
    const float* __restrict__ d2w, const float* __restrict__ d2b, float* __restrict__ out){
  const float kinv[6] = {1.f/800.f, 1.f/640.f, 1.f/512.f, 1.f/410.f, 1.f/328.f, 1.f/263.f};
  int g = blockIdx.x, j = threadIdx.x;
  __shared__ float fl[256];
  __shared__ float hd[512];
  if(j < 128){
    float s = 0.f;
    #pragma unroll
    for(int l=0;l<6;l++){
      float ls = 0.f;
      for(int c=0;c<POOL_NB;c++)
        ls += sumstage[(size_t)((l*POOL_NB + c)*NGR + g)*HDIM + j];
      s += ls * kinv[l];
    }
    fl[j] = s;
  } else if(j < 256){
    int f = j - 128;
    float m = 0.f;
    #pragma unroll
    for(int l=0;l<6;l++){
      float lm = -FLT_MAX;
      for(int c=0;c<POOL_NB;c++)
        lm = fmaxf(lm, maxstage[(size_t)((l*POOL_NB + c)*NGR + g)*HDIM + f]);
      m += lm;
    }
    fl[j] = m;
  }
  __syncthreads();
  float acc = d1b[j];
  for(int i=0;i<256;i++) acc += fl[i]*d1w[i*512+j];
  hd[j] = fmaxf(acc, 0.f);
  __syncthreads();
  if(j < 10){
    float a = d2b[j];
    for(int i=0;i<512;i++) a += hd[i]*d2w[i*10+j];
    out[g*10+j] = a;
  }
}

extern "C" void kernel_launch(void* const* d_in, const int* in_sizes, int n_in,
                              void* d_out, int out_size, void* d_ws, size_t ws_size,
                              hipStream_t stream) {
  const float* x    = (const float*)d_in[0];
  const int* ei     = (const int*)d_in[1];
  const float* ew   = (const float*)d_in[3];
  const float* conv1w = (const float*)d_in[4];
  const float* convw  = (const float*)d_in[5];
  const float* convb  = (const float*)d_in[6];
  const float* bng    = (const float*)d_in[7];
  const float* bnb    = (const float*)d_in[8];
  const float* bnm    = (const float*)d_in[9];
  const float* bnv    = (const float*)d_in[10];
  const float* poolw  = (const float*)d_in[11];
  const float* d1w    = (const float*)d_in[12];
  const float* d1b    = (const float*)d_in[13];
  const float* d2w    = (const float*)d_in[14];
  const float* d2b    = (const float*)d_in[15];
  float* out = (float*)d_out;

  char* w = (char*)d_ws;
  float* hbufA = (float*)w; w += (size_t)64000*128*4;   // layer output ping
  float* hbufB = (float*)w; w += (size_t)64000*128*4;   // layer output pong
  long long* ec = (long long*)w; w += (size_t)NE*8;     // static (w, src_orig), dst-bucketed
  int*   rp    = (int*)w;   w += (size_t)NGR*RPS*4;
  int*   pcnt  = (int*)w;   w += (size_t)256*NPG0*4;
  float* pdeg  = (float*)w; w += (size_t)256*NPG0*4;
  float* dinvz = (float*)w; w += (size_t)64000*4;       // 0 == node dead (alive indicator)
  float* gsc   = (float*)w; w += (size_t)64000*4;       // dinv_new * topk_val (0 == dead)
  float* score = (float*)w; w += (size_t)64000*4;
  float* vals  = (float*)w; w += (size_t)51200*4;
  int*   listA = (int*)w;   w += (size_t)51200*4;
  int*   listB = (int*)w;   w += (size_t)51200*4;
  float* invno = (float*)w; w += 64;
  float* sumstage = (float*)w; w += (size_t)6*POOL_NB*NGR*HDIM*4;
  float* maxstage = (float*)w; w += (size_t)6*POOL_NB*NGR*HDIM*4;
  unsigned short* whi = (unsigned short*)w; w += (size_t)6*16384*2;  // bf16-hi weights, panel-major
  unsigned short* wlo = (unsigned short*)w; w += (size_t)6*16384*2;  // bf16-lo weights

  k_wsplit<<<6,256,0,stream>>>(conv1w, convw, poolw, whi, wlo, invno);

  const int ns[6]={1000,800,640,512,410,328};
  const int ks[6]={800,640,512,410,328,263};

  // ---- one-time CSR build (original ids): count partials, then fused scan+scatter ----
  k_count0<<<256,256,0,stream>>>(ei+NE, ew, pcnt, pdeg);
  k_build<<<64,1024,0,stream>>>(pcnt, pdeg, ei, ei+NE, ew, rp, dinvz, gsc, ec);

  // ---- layer 0 (input = x, 64 cols) ----
  k_fused<64><<<4000,256,0,stream>>>(nullptr, rp, ec, dinvz, gsc, x, whi, wlo,
                                     convb, bng, bnb, bnm, bnv, poolw, invno,
                                     hbufA, score);
  k_topk<<<64,512,0,stream>>>(1000, 800, score, nullptr, vals, listA, dinvz, gsc);
  k_gpd<<<64*POOL_NB,256,0,stream>>>(800, 1, hbufA, vals, listA,
                                     sumstage, maxstage, rp, ec, dinvz, gsc);

  // ---- layers 1..5 (ping-pong h buffers: fused reads hin, writes hout) ----
  int* cur = listA; int* nxt = listB;
  float* hin = hbufA; float* hot = hbufB;
  for(int i=1;i<6;i++){
    int n = ns[i], k = ks[i];
    k_fused<128><<<4*n,256,0,stream>>>(cur, rp, ec, dinvz, gsc, hin,
                                       whi + (size_t)i*16384, wlo + (size_t)i*16384,
                                       convb+i*128, bng+i*128, bnb+i*128, bnm+i*128,
                                       bnv+i*128, poolw+i*128, invno+i,
                                       hot, score);
    k_topk<<<64,512,0,stream>>>(n, k, score, cur, vals, nxt, dinvz, gsc);
    k_gpd<<<64*POOL_NB,256,0,stream>>>(k, (i<5)?1:0, hot, vals, nxt,
                                       sumstage + (size_t)i*POOL_NB*NGR*HDIM,
                                       maxstage + (size_t)i*POOL_NB*NGR*HDIM,
                                       rp, ec, dinvz, gsc);
    int* tmp = cur; cur = nxt; nxt = tmp;
    float* htmp = hin; hin = hot; hot = htmp;
  }

  k_head<<<64,512,0,stream>>>(sumstage, maxstage, d1w, d1b, d2w, d2b, out);
}